// Round 5
// baseline (92.764 us; speedup 1.0000x reference)
//
#include <hip/hip_runtime.h>

// out[b,n] = relu( sum_d x[b, idx[n,d]] * w[n,d] )
//   x: (B=256, N=16384) f32, w: (N,32) f32, idx: (N,32) i32, out: (B,N) f32
//
// R5: K2 was MLP-starved (VGPR=32 from launch_bounds(256,8) -> ~2 loads in
// flight against ~300cyc latency; R3 byte-halving and R4 segment-halving both
// under-delivered). New K2: broadcast-load idx/w into registers (no staging
// barrier), 4-deep software-pipelined gather window = 16 outstanding 1-KiB
// line loads per wave. Plain stores (nontemporal showed 2x WRITE_SIZE).
//   xc[chunk=4][N][64] fp16: 2 MiB/chunk, pinned to XCD pairs via blockIdx&3.

#define B      256
#define N      16384
#define DEG    32
#define NT     32        // n per block in K2
#define NCHUNK 4
#define CB     64        // b per chunk (fp16 row = 128 B = one cache line)

typedef float v4f __attribute__((ext_vector_type(4)));
typedef _Float16 h8v __attribute__((ext_vector_type(8)));

__global__ __launch_bounds__(256) void chunk_transpose_f16_kernel(
    const float* __restrict__ x, _Float16* __restrict__ xc) {
    __shared__ float tile[64][65];               // [b_local][j_local], +1 pad
    const int t     = threadIdx.x;
    const int j0    = blockIdx.x * 64;           // N/64 = 256
    const int chunk = blockIdx.y;                // b0 = chunk*64 (B/64 = 4)
    const int c4 = t & 15;
    const int r  = t >> 4;

#pragma unroll
    for (int it = 0; it < 4; ++it) {
        const int row = r + it * 16;             // b_local
        const float4 v = *(const float4*)&x[(size_t)(chunk * 64 + row) * N + j0 + 4 * c4];
        tile[row][4 * c4 + 0] = v.x;
        tile[row][4 * c4 + 1] = v.y;
        tile[row][4 * c4 + 2] = v.z;
        tile[row][4 * c4 + 3] = v.w;
    }
    __syncthreads();

    const int wv = t >> 6, l = t & 63;
    const int a  = l & 7;                        // b-octet: b = 8a..8a+7
    _Float16* dst = xc + (size_t)chunk * N * CB + 8 * a;
#pragma unroll
    for (int p = 0; p < 2; ++p) {
        const int j = p * 32 + wv * 8 + (l >> 3);
        h8v h;
#pragma unroll
        for (int k = 0; k < 8; ++k) h[k] = (_Float16)tile[8 * a + k][j];
        *(h8v*)&dst[(size_t)(j0 + j) * CB] = h;  // 8 rows x 128 B = 1 KiB contiguous
    }
}

__global__ __launch_bounds__(256) void gather_dot_f16_kernel(
    const _Float16* __restrict__ xc, const float* __restrict__ w,
    const int* __restrict__ idx, float* __restrict__ out) {
    __shared__ float tile[64 * 33];              // out transpose tile only

    const int t     = threadIdx.x;
    const int chunk = blockIdx.x & 3;
    const int nb    = (int)(blockIdx.x >> 2) * NT;
    const int wv    = t >> 6;
    const int l     = t & 63;
    const int slot  = wv * 8 + (l >> 3);         // n_local 0..31
    const int a     = l & 7;                     // b-octet: b = 8a..8a+7
    const int n     = nb + slot;

    // Broadcast loads (8 lanes/a-group share the address; 128 B/wave-instr, L2-hot)
    const int4*   idx4 = (const int4*)(idx + (size_t)n * DEG);
    const float4* w4p  = (const float4*)(w   + (size_t)n * DEG);
    int4 j[8];
#pragma unroll
    for (int d4 = 0; d4 < 8; ++d4) j[d4] = idx4[d4];
    float4 wq[8];
#pragma unroll
    for (int d4 = 0; d4 < 8; ++d4) wq[d4] = w4p[d4];

    const _Float16* xcb = xc + (size_t)chunk * (N * CB) + 8 * a;

#define GATHER(g, jv)                                   \
    g[0] = *(const h8v*)&xcb[(size_t)(jv).x * CB];      \
    g[1] = *(const h8v*)&xcb[(size_t)(jv).y * CB];      \
    g[2] = *(const h8v*)&xcb[(size_t)(jv).z * CB];      \
    g[3] = *(const h8v*)&xcb[(size_t)(jv).w * CB];

    float acc[8] = {0.f, 0.f, 0.f, 0.f, 0.f, 0.f, 0.f, 0.f};

#define CONSUME(g, W)                                                     \
    {                                                                     \
        _Pragma("unroll")                                                 \
        for (int k = 0; k < 8; ++k) acc[k] = fmaf((W).x, (float)g[0][k], acc[k]); \
        _Pragma("unroll")                                                 \
        for (int k = 0; k < 8; ++k) acc[k] = fmaf((W).y, (float)g[1][k], acc[k]); \
        _Pragma("unroll")                                                 \
        for (int k = 0; k < 8; ++k) acc[k] = fmaf((W).z, (float)g[2][k], acc[k]); \
        _Pragma("unroll")                                                 \
        for (int k = 0; k < 8; ++k) acc[k] = fmaf((W).w, (float)g[3][k], acc[k]); \
    }

    // 4-deep pipeline: 16 gather loads outstanding in steady state.
    h8v g0[4], g1[4], g2[4], g3[4];
    GATHER(g0, j[0]);
    GATHER(g1, j[1]);
    GATHER(g2, j[2]);
    GATHER(g3, j[3]);

    CONSUME(g0, wq[0]); GATHER(g0, j[4]);
    CONSUME(g1, wq[1]); GATHER(g1, j[5]);
    CONSUME(g2, wq[2]); GATHER(g2, j[6]);
    CONSUME(g3, wq[3]); GATHER(g3, j[7]);
    CONSUME(g0, wq[4]);
    CONSUME(g1, wq[5]);
    CONSUME(g2, wq[6]);
    CONSUME(g3, wq[7]);

#undef GATHER
#undef CONSUME

    __syncthreads();                             // (uniform; orders tile reuse)
#pragma unroll
    for (int k = 0; k < 8; ++k)
        tile[(8 * a + k) * 33 + slot] = acc[k];  // banks (8a+k+slot)%32: 2-way
    __syncthreads();

#pragma unroll
    for (int p = 0; p < 2; ++p) {
        const int b = wv * 16 + p * 8 + (l >> 3);
        const int c = l & 7;
        v4f v;
        v.x = fmaxf(tile[b * 33 + 4 * c + 0], 0.f);
        v.y = fmaxf(tile[b * 33 + 4 * c + 1], 0.f);
        v.z = fmaxf(tile[b * 33 + 4 * c + 2], 0.f);
        v.w = fmaxf(tile[b * 33 + 4 * c + 3], 0.f);
        // 8 lanes x 16 B = 128 B contiguous per b-row; full lines per wave
        *(v4f*)&out[(size_t)(chunk * CB + b) * N + nb + 4 * c] = v;
    }
}

extern "C" void kernel_launch(void* const* d_in, const int* in_sizes, int n_in,
                              void* d_out, int out_size, void* d_ws, size_t ws_size,
                              hipStream_t stream) {
    const float* x   = (const float*)d_in[0];    // (B, N)
    const float* w   = (const float*)d_in[1];    // (N, DEG)
    const int*   idx = (const int*)d_in[2];      // (N, DEG)
    float* out = (float*)d_out;                  // (B, N)
    _Float16* xc = (_Float16*)d_ws;              // [4][N][64] fp16 = 8 MiB

    dim3 tgrid(N / 64, B / 64);                  // 256 x 4
    chunk_transpose_f16_kernel<<<tgrid, 256, 0, stream>>>(x, xc);

    gather_dot_f16_kernel<<<(N / NT) * NCHUNK, 256, 0, stream>>>(xc, w, idx, out);
}